// Round 14
// baseline (247.555 us; speedup 1.0000x reference)
//
#include <hip/hip_runtime.h>
#include <hip/hip_bf16.h>

#define B_      16
#define N_TOK   1024
#define DIM_    768
#define HEADS_  12
#define DHEAD   64
#define KRES_   9

#define QKV_E   (12582912)           // B*HEADS*N*DHEAD
#define ROWS_   (B_*HEADS_*N_TOK)    // 196608
#define ACH     4                    // attn n-chunks per (b,h)
#define PARTN   1536                 // mean-partials per q/k (128 by * 12 bx)

typedef __attribute__((ext_vector_type(8))) short bf16x8;
typedef __attribute__((ext_vector_type(4))) short s16x4;
typedef __attribute__((ext_vector_type(4))) float f32x4;

__device__ inline short f2b(float f) {
  unsigned u = __builtin_bit_cast(unsigned, f);
  u += 0x7fff + ((u >> 16) & 1);   // round-to-nearest-even
  return (short)(u >> 16);
}
__device__ inline float b2f(short s) {
  unsigned u = ((unsigned)(unsigned short)s) << 16;
  return __builtin_bit_cast(float, u);
}
__device__ inline float bitval(unsigned long long m, int dd) {
  return ((m >> dd) & 1ull) ? 1.0f : 0.0f;
}

__device__ inline void gload16(const short* g, short* l) {
  __builtin_amdgcn_global_load_lds(
      (const __attribute__((address_space(1))) void*)g,
      (__attribute__((address_space(3))) void*)l, 16, 0, 0);
}

// ---------------------------------------------------------------------------
// x (f32) -> bf16, vectorized 8/thread
// ---------------------------------------------------------------------------
__global__ __launch_bounds__(256) void cvt_bf16_kernel(
    const float* __restrict__ in, short* __restrict__ out, int n8)
{
  int i = blockIdx.x * 256 + threadIdx.x;
  if (i >= n8) return;
  float4 a = ((const float4*)in)[2 * i];
  float4 b = ((const float4*)in)[2 * i + 1];
  bf16x8 v;
  v[0]=f2b(a.x); v[1]=f2b(a.y); v[2]=f2b(a.z); v[3]=f2b(a.w);
  v[4]=f2b(b.x); v[5]=f2b(b.y); v[6]=f2b(b.z); v[7]=f2b(b.w);
  ((bf16x8*)out)[i] = v;
}

// ---------------------------------------------------------------------------
// fused dual transpose: f32 [768][C] -> bf16 [C][768] for w_qkv (C=2304,
// blocks 0..35 x) and w_proj (C=768, blocks 36..47 x). One dispatch.
// ---------------------------------------------------------------------------
__global__ __launch_bounds__(256) void transpose_cvt2_kernel(
    const float* __restrict__ in1, short* __restrict__ out1,
    const float* __restrict__ in2, short* __restrict__ out2)
{
  __shared__ short t[64][65];
  const bool second = blockIdx.x >= 36;
  const float* in  = second ? in2  : in1;
  short*       out = second ? out2 : out1;
  const int C = second ? 768 : 2304;
  const int R = 768;
  int c0 = (second ? (blockIdx.x - 36) : blockIdx.x) * 64;
  int r0 = blockIdx.y * 64;
#pragma unroll
  for (int p = 0; p < 4; ++p) {
    int r = (threadIdx.x >> 4) + p * 16;
    int c = (threadIdx.x & 15) * 4;
    float4 v = *(const float4*)(in + (size_t)(r0 + r) * C + c0 + c);
    t[c][r] = f2b(v.x); t[c + 1][r] = f2b(v.y);
    t[c + 2][r] = f2b(v.z); t[c + 3][r] = f2b(v.w);
  }
  __syncthreads();
#pragma unroll
  for (int p = 0; p < 4; ++p) {
    int oc = (threadIdx.x >> 4) + p * 16;
    int orr = (threadIdx.x & 15) * 4;
    s16x4 v = { t[oc][orr], t[oc][orr + 1], t[oc][orr + 2], t[oc][orr + 3] };
    *(s16x4*)(out + (size_t)(c0 + oc) * R + r0 + orr) = v;
  }
}

// ---------------------------------------------------------------------------
// 128x128-tile GEMM, BK=64, 4 waves, single-buffered 32 KB LDS, plain
// 2-barrier loop (32 MFMA between barriers). Both-sides LDS XOR-swizzle ->
// bank-conflict free (round-10 verified). XCD-chunked block swizzle.
// MODE 0: fused q/k row-norm + mean partials, scatter bf16 -> [B,h,N,d].
// MODE 1: f32 + bias -> out.
// ---------------------------------------------------------------------------
template<int MODE>
__global__ __launch_bounds__(256) void gemm128(
    const short* __restrict__ A, const short* __restrict__ BT,
    int N, int K, int nxblk,
    short* __restrict__ qkv_out, float* __restrict__ proj_out,
    const float* __restrict__ bias, float* __restrict__ partials)
{
  __shared__ short As[128 * 64];   // 16 KB, swizzled k within each row
  __shared__ short Bs[128 * 64];   // 16 KB
  __shared__ float sred[4];

  const int tid  = threadIdx.x;
  const int lane = tid & 63;
  const int wid  = tid >> 6;
  const int wr   = wid >> 1, wc = wid & 1;

  const int nwg = (int)gridDim.x;
  const int cpx = nwg >> 3;
  const int swz = (blockIdx.x & 7) * cpx + (blockIdx.x >> 3);
  const int bx  = swz % nxblk, by = swz / nxblk;
  const int rowBase = by << 7;
  const int colBase = bx << 7;

  const int fr = lane & 15;
  const int fq = lane >> 4;        // 0..3

  const int srow8 = tid >> 3;                         // 0..31
  const int koff  = ((tid & 7) ^ (srow8 & 7)) << 3;   // pre-swizzled source k
  const short* ApS = A  + (size_t)(rowBase + srow8) * K + koff;
  const short* BpS = BT + (size_t)(colBase + srow8) * K + koff;
  short* dA = As + tid * 8;        // linear dest: byte off = 16*tid (+i*4KB)
  short* dB = Bs + tid * 8;

  int aoff[4], boff[4];
#pragma unroll
  for (int mf = 0; mf < 4; ++mf) {
    int r = wr * 64 + mf * 16 + fr;
    aoff[mf] = r * 64 + (((r >> 2) & 1) << 5) + ((fq ^ (r & 3)) << 3);
  }
#pragma unroll
  for (int nf = 0; nf < 4; ++nf) {
    int r = wc * 64 + nf * 16 + fr;
    boff[nf] = r * 64 + (((r >> 2) & 1) << 5) + ((fq ^ (r & 3)) << 3);
  }

  f32x4 acc[4][4];
#pragma unroll
  for (int i = 0; i < 4; ++i)
#pragma unroll
    for (int j = 0; j < 4; ++j) acc[i][j] = f32x4{0.f, 0.f, 0.f, 0.f};

  for (int k0 = 0; k0 < K; k0 += 64) {
    __syncthreads();
#pragma unroll
    for (int i = 0; i < 4; ++i) {
      gload16(ApS + (size_t)(i * 32) * K + k0, dA + i * 2048);
      gload16(BpS + (size_t)(i * 32) * K + k0, dB + i * 2048);
    }
    __syncthreads();

#pragma unroll
    for (int ks = 0; ks < 2; ++ks) {
      const int kx = ks << 5;
      bf16x8 a[4], b[4];
#pragma unroll
      for (int mf = 0; mf < 4; ++mf)
        a[mf] = *(const bf16x8*)(As + (aoff[mf] ^ kx));
#pragma unroll
      for (int nf = 0; nf < 4; ++nf)
        b[nf] = *(const bf16x8*)(Bs + (boff[nf] ^ kx));
#pragma unroll
      for (int mf = 0; mf < 4; ++mf)
#pragma unroll
        for (int nf = 0; nf < 4; ++nf)
          acc[mf][nf] = __builtin_amdgcn_mfma_f32_16x16x32_bf16(a[mf], b[nf], acc[mf][nf], 0, 0, 0);
    }
  }

  // ---- epilogue: D frag layout col = lane&15, row = fq*4 + e ----
  if (MODE == 0) {
    const int b    = rowBase >> 10;
    const int n0   = (rowBase & 1023) + wr * 64 + (fq << 2);
    const int part = colBase / 768;                   // block-uniform
    const int hd   = ((colBase - part * 768) >> 6) + wc;
    float psum = 0.f;

    if (part < 2) {
      float ss[4][4];
#pragma unroll
      for (int i = 0; i < 4; ++i)
#pragma unroll
        for (int e = 0; e < 4; ++e) {
          float s = 0.f;
#pragma unroll
          for (int j = 0; j < 4; ++j) s = fmaf(acc[i][j][e], acc[i][j][e], s);
          ss[i][e] = s;
        }
#pragma unroll
      for (int m = 1; m < 16; m <<= 1)
#pragma unroll
        for (int i = 0; i < 4; ++i)
#pragma unroll
          for (int e = 0; e < 4; ++e) ss[i][e] += __shfl_xor(ss[i][e], m);
#pragma unroll
      for (int i = 0; i < 4; ++i)
#pragma unroll
        for (int e = 0; e < 4; ++e) ss[i][e] = rsqrtf(ss[i][e]);
#pragma unroll
      for (int i = 0; i < 4; ++i)
#pragma unroll
        for (int j = 0; j < 4; ++j)
#pragma unroll
          for (int e = 0; e < 4; ++e) {
            acc[i][j][e] *= ss[i][e];
            psum += acc[i][j][e];
          }
    }

    const size_t hbase = (size_t)part * QKV_E + ((size_t)(b * 12 + hd) << 16);
#pragma unroll
    for (int j = 0; j < 4; ++j) {
      const int dd = j * 16 + fr;
#pragma unroll
      for (int i = 0; i < 4; ++i)
#pragma unroll
        for (int e = 0; e < 4; ++e)
          qkv_out[hbase + ((size_t)(n0 + i * 16 + e) << 6) + dd] = f2b(acc[i][j][e]);
    }

    if (part < 2) {          // block-uniform branch: barrier is safe
#pragma unroll
      for (int m = 1; m < 64; m <<= 1) psum += __shfl_xor(psum, m);
      if (lane == 0) sred[wid] = psum;
      __syncthreads();
      if (tid == 0)
        partials[part * PARTN + by * 12 + (bx - part * 6)] =
            sred[0] + sred[1] + sred[2] + sred[3];
    }
  } else {
    const int gr0 = rowBase + wr * 64 + (fq << 2);
#pragma unroll
    for (int j = 0; j < 4; ++j) {
      int gc = colBase + wc * 64 + j * 16 + fr;
      float bj = bias[gc];
#pragma unroll
      for (int i = 0; i < 4; ++i)
#pragma unroll
        for (int e = 0; e < 4; ++e)
          proj_out[(size_t)(gr0 + i * 16 + e) * N + gc] = acc[i][j][e] + bj;
    }
  }
}

__global__ __launch_bounds__(256) void mean_reduce_kernel(
    const float* __restrict__ partials, float* __restrict__ means)
{
  float sq = 0.f, sk = 0.f;
  for (int i = threadIdx.x; i < PARTN; i += 256) {
    sq += partials[i]; sk += partials[PARTN + i];
  }
#pragma unroll
  for (int o = 32; o; o >>= 1) { sq += __shfl_xor(sq, o); sk += __shfl_xor(sk, o); }
  __shared__ float s[8];
  int wid = threadIdx.x >> 6, lane = threadIdx.x & 63;
  if (lane == 0) { s[wid] = sq; s[4 + wid] = sk; }
  __syncthreads();
  if (threadIdx.x == 0) {
    means[0] = (s[0] + s[1] + s[2] + s[3]) / 12582912.f;
    means[1] = (s[4] + s[5] + s[6] + s[7]) / 12582912.f;
  }
}

// ---------------------------------------------------------------------------
// attn partials via MFMA (round-12 verified: 80us scalar -> MFMA)
// ---------------------------------------------------------------------------
__global__ __launch_bounds__(256) void attn_part_kernel(
    const short* __restrict__ k, const short* __restrict__ v,
    const float* __restrict__ means, float* __restrict__ part)
{
  __shared__ short kt[64][136];
  __shared__ short vt[64][136];
  const int tid = threadIdx.x, lane = tid & 63, w = tid >> 6;
  const int bh = blockIdx.x >> 2;
  const int c  = blockIdx.x & 3;
  const float mk = means[1];
  const short* kb = k + ((size_t)bh << 16);
  const short* vb = v + ((size_t)bh << 16);

  const int nl = tid & 31;         // token-within-32
  const int dg = tid >> 5;         // d-group 0..7
  const int fr = lane & 15, fq = lane >> 4;

  f32x4 acc[4];
#pragma unroll
  for (int e = 0; e < 4; ++e) acc[e] = f32x4{0.f, 0.f, 0.f, 0.f};

  for (int s = 0; s < 2; ++s) {
    __syncthreads();               // prior compute done before overwrite
#pragma unroll
    for (int p = 0; p < 4; ++p) {
      int r = p * 32 + nl;         // 0..127 local token
      int n = (c << 8) + (s << 7) + r;
      bf16x8 kv8 = *(const bf16x8*)(kb + (n << 6) + dg * 8);
      bf16x8 vv8 = *(const bf16x8*)(vb + (n << 6) + dg * 8);
#pragma unroll
      for (int j = 0; j < 8; ++j) {
        kt[dg * 8 + j][r] = (b2f(kv8[j]) > mk) ? (short)0x3F80 : (short)0;
        vt[dg * 8 + j][r] = vv8[j];
      }
    }
    __syncthreads();
#pragma unroll
    for (int ks = 0; ks < 4; ++ks) {
      const int nloc = ks * 32 + fq * 8;
      bf16x8 af = *(const bf16x8*)(&kt[w * 16 + fr][nloc]);
#pragma unroll
      for (int nf = 0; nf < 4; ++nf) {
        bf16x8 bfr = *(const bf16x8*)(&vt[nf * 16 + fr][nloc]);
        acc[nf] = __builtin_amdgcn_mfma_f32_16x16x32_bf16(af, bfr, acc[nf], 0, 0, 0);
      }
    }
  }
  float* pp = part + ((size_t)blockIdx.x << 12);
#pragma unroll
  for (int nf = 0; nf < 4; ++nf)
#pragma unroll
    for (int ee = 0; ee < 4; ++ee)
      pp[(w * 16 + fq * 4 + ee) * 64 + nf * 16 + fr] = acc[nf][ee];
}

// separate reduce (r10 lesson: fusing into out_kernel spills col[] to scratch)
__global__ __launch_bounds__(256) void attn_reduce_kernel(
    const float* __restrict__ part, float* __restrict__ attn)
{
  int idx = blockIdx.x * 256 + threadIdx.x;   // over 192*4096
  int bh  = idx >> 12;
  int off = idx & 4095;
  float s = 0.f;
#pragma unroll
  for (int c = 0; c < ACH; ++c)
    s += part[(((size_t)bh * ACH + c) << 12) + off];
  attn[idx] = s;
}

// ---------------------------------------------------------------------------
// out rows: o = 0.5 v + (1/pi) qbits.attn ; normalize ; + depthwise conv.
// Round-12 single-row structure (45us verified). ONLY change: the 64-step
// serial fmaf chain -> 4 interleaved accumulators (+3 VGPR), and
// __launch_bounds__(256,3) so the allocator budgets ~170 VGPR instead of
// squeezing for 8 waves and spilling col[64] (r10/r13 failure: VGPR=48).
// ---------------------------------------------------------------------------
__global__ __launch_bounds__(256, 3) void out_kernel(
    const short* __restrict__ q, const short* __restrict__ v,
    const float* __restrict__ attn, const float* __restrict__ means,
    const float* __restrict__ wd, short* __restrict__ mid)
{
  __shared__ short v_s[136 * 64];     // rows n0-4 .. n0+131
  int tid = threadIdx.x, lane = tid & 63, wid = tid >> 6;
  int bh = blockIdx.x >> 3;
  int n0 = (blockIdx.x & 7) << 7;
  int h  = bh % 12;
  int b  = bh / 12;

  const short* vb = v + ((size_t)bh << 16);
  for (int i = tid; i < 2176; i += 256) {
    int r = i >> 4, c = (i & 15) << 2;
    int nn = n0 - 4 + r;
    s16x4 val = {0, 0, 0, 0};
    if (nn >= 0 && nn < N_TOK) val = *(const s16x4*)(vb + (nn << 6) + c);
    *(s16x4*)(v_s + (i << 2)) = val;
  }

  const float* ag = attn + ((size_t)bh << 12) + lane;
  float col[64];
#pragma unroll
  for (int dd = 0; dd < 64; ++dd) col[dd] = ag[dd << 6];

  float mq = means[0];
  float wc[9];
#pragma unroll
  for (int j = 0; j < 9; ++j) wc[j] = wd[h * 9 + j];
  __syncthreads();

  const short* qb = q + ((size_t)bh << 16);
  for (int t = 0; t < 32; ++t) {
    int ln = (wid << 5) + t;
    int n  = n0 + ln;
    float qv = b2f(qb[(n << 6) + lane]);
    unsigned long long qmask = __ballot((qv - mq) > 0.f);
    float a0 = 0.f, a1 = 0.f, a2 = 0.f, a3 = 0.f;
#pragma unroll
    for (int dd = 0; dd < 64; dd += 4) {
      a0 = fmaf(bitval(qmask, dd),     col[dd],     a0);
      a1 = fmaf(bitval(qmask, dd + 1), col[dd + 1], a1);
      a2 = fmaf(bitval(qmask, dd + 2), col[dd + 2], a2);
      a3 = fmaf(bitval(qmask, dd + 3), col[dd + 3], a3);
    }
    float acc = (a0 + a1) + (a2 + a3);
    float vv = b2f(v_s[((ln + 4) << 6) + lane]);
    float o = 0.5f * vv + acc * 0.3183098861837907f;
    float ss = o * o;
#pragma unroll
    for (int off = 32; off; off >>= 1) ss += __shfl_xor(ss, off);
    o *= rsqrtf(ss);
#pragma unroll
    for (int j = 0; j < 9; ++j)
      o += wc[j] * b2f(v_s[((ln + j) << 6) + lane]);
    mid[(size_t)((b << 10) | n) * 768 + (h << 6) + lane] = f2b(o);
  }
}

extern "C" void kernel_launch(void* const* d_in, const int* in_sizes, int n_in,
                              void* d_out, int out_size, void* d_ws, size_t ws_size,
                              hipStream_t stream) {
  (void)in_sizes; (void)n_in; (void)out_size; (void)ws_size;
  const float* x       = (const float*)d_in[0];
  const float* w_qkv   = (const float*)d_in[3];
  const float* w_dconv = (const float*)d_in[4];
  const float* w_proj  = (const float*)d_in[5];
  const float* b_proj  = (const float*)d_in[6];

  // ---- workspace layout (phase-safe aliasing), ~130.5 MB ----
  char* ws = (char*)d_ws;
  short* qbuf = (short*)ws;                         // 3*QKV_E shorts
  short* kbuf = qbuf + QKV_E;
  short* vbuf = kbuf + QKV_E;
  char*  r2   = ws + (size_t)3 * QKV_E * 2;         // 3.54 MB region:
  short* wqkvT    = (short*)r2;                     //   phases 0-1 (3.54 MB)
  float* attn     = (float*)r2;                     //   phases 4-5 (3.15 MB)
  short* mid  = (short*)(r2 + 3538944);             // 25.2 MB, phases 5-6
  float* partials = (float*)mid;                    //   phases 1-2 (12 KB) —
                                                    //   mid unwritten till ph5
  char*  r4   = (char*)mid + (size_t)16384 * 768 * 2;
  short* xb        = (short*)r4;                    // 25.2 MB, phases 0-1
  float* attn_part = (float*)r4;                    //   reused ph 3-4 (12.6 MB)
  short* wprojT = (short*)(r4 + (size_t)QKV_E * 2); // 1.18 MB, phases 0,6
  float* means  = (float*)((char*)wprojT + (size_t)768 * 768 * 2);

  // 0) convert x -> bf16; transpose+convert both weights (one dispatch)
  cvt_bf16_kernel<<<QKV_E / 8 / 256, 256, 0, stream>>>(x, xb, QKV_E / 8);
  dim3 gt(48, 12);
  transpose_cvt2_kernel<<<gt, 256, 0, stream>>>(w_qkv, wqkvT, w_proj, wprojT);

  // 1) QKV GEMM (+fused q/k row-norm + mean partials) -> q,k,v [B,h,N,d]
  gemm128<0><<<(2304 / 128) * (16384 / 128), 256, 0, stream>>>(
      xb, wqkvT, 2304, 768, 18, qbuf, nullptr, nullptr, partials);

  // 2) global means of normalized q,k
  mean_reduce_kernel<<<1, 256, 0, stream>>>(partials, means);

  // 3) attn partials = binarized(k)^T v via MFMA
  attn_part_kernel<<<B_ * HEADS_ * ACH, 256, 0, stream>>>(kbuf, vbuf, means, attn_part);

  // 4) reduce partials -> attn [192][64][64]
  attn_reduce_kernel<<<B_ * HEADS_ * 4096 / 256, 256, 0, stream>>>(attn_part, attn);

  // 5) out rows -> mid bf16 [B,N,768]
  out_kernel<<<ROWS_ / 128, 256, 0, stream>>>(qbuf, vbuf, attn, means, w_dconv, mid);

  // 6) projection: mid @ wprojT^T + b_proj -> d_out f32
  gemm128<1><<<(768 / 128) * (16384 / 128), 256, 0, stream>>>(
      mid, wprojT, 768, 768, 6, nullptr, (float*)d_out, b_proj, nullptr);
}

// Round 15
// 174.432 us; speedup vs baseline: 1.4192x; 1.4192x over previous
//
#include <hip/hip_runtime.h>
#include <hip/hip_bf16.h>

#define B_      16
#define N_TOK   1024
#define DIM_    768
#define HEADS_  12
#define DHEAD   64
#define KRES_   9

#define QKV_E   (12582912)           // B*HEADS*N*DHEAD
#define ROWS_   (B_*HEADS_*N_TOK)    // 196608
#define ACH     4                    // attn n-chunks per (b,h)
#define PARTN   1536                 // mean-partials per q/k (128 by * 12 bx)

typedef __attribute__((ext_vector_type(8))) short bf16x8;
typedef __attribute__((ext_vector_type(4))) short s16x4;
typedef __attribute__((ext_vector_type(4))) float f32x4;

__device__ inline short f2b(float f) {
  unsigned u = __builtin_bit_cast(unsigned, f);
  u += 0x7fff + ((u >> 16) & 1);   // round-to-nearest-even
  return (short)(u >> 16);
}
__device__ inline float b2f(short s) {
  unsigned u = ((unsigned)(unsigned short)s) << 16;
  return __builtin_bit_cast(float, u);
}

__device__ inline void gload16(const short* g, short* l) {
  __builtin_amdgcn_global_load_lds(
      (const __attribute__((address_space(1))) void*)g,
      (__attribute__((address_space(3))) void*)l, 16, 0, 0);
}

// ---------------------------------------------------------------------------
// x (f32) -> bf16, vectorized 8/thread
// ---------------------------------------------------------------------------
__global__ __launch_bounds__(256) void cvt_bf16_kernel(
    const float* __restrict__ in, short* __restrict__ out, int n8)
{
  int i = blockIdx.x * 256 + threadIdx.x;
  if (i >= n8) return;
  float4 a = ((const float4*)in)[2 * i];
  float4 b = ((const float4*)in)[2 * i + 1];
  bf16x8 v;
  v[0]=f2b(a.x); v[1]=f2b(a.y); v[2]=f2b(a.z); v[3]=f2b(a.w);
  v[4]=f2b(b.x); v[5]=f2b(b.y); v[6]=f2b(b.z); v[7]=f2b(b.w);
  ((bf16x8*)out)[i] = v;
}

// ---------------------------------------------------------------------------
// fused dual transpose: f32 [768][C] -> bf16 [C][768] for w_qkv (C=2304,
// blocks 0..35 x) and w_proj (C=768, blocks 36..47 x). One dispatch.
// ---------------------------------------------------------------------------
__global__ __launch_bounds__(256) void transpose_cvt2_kernel(
    const float* __restrict__ in1, short* __restrict__ out1,
    const float* __restrict__ in2, short* __restrict__ out2)
{
  __shared__ short t[64][65];
  const bool second = blockIdx.x >= 36;
  const float* in  = second ? in2  : in1;
  short*       out = second ? out2 : out1;
  const int C = second ? 768 : 2304;
  const int R = 768;
  int c0 = (second ? (blockIdx.x - 36) : blockIdx.x) * 64;
  int r0 = blockIdx.y * 64;
#pragma unroll
  for (int p = 0; p < 4; ++p) {
    int r = (threadIdx.x >> 4) + p * 16;
    int c = (threadIdx.x & 15) * 4;
    float4 v = *(const float4*)(in + (size_t)(r0 + r) * C + c0 + c);
    t[c][r] = f2b(v.x); t[c + 1][r] = f2b(v.y);
    t[c + 2][r] = f2b(v.z); t[c + 3][r] = f2b(v.w);
  }
  __syncthreads();
#pragma unroll
  for (int p = 0; p < 4; ++p) {
    int oc = (threadIdx.x >> 4) + p * 16;
    int orr = (threadIdx.x & 15) * 4;
    s16x4 v = { t[oc][orr], t[oc][orr + 1], t[oc][orr + 2], t[oc][orr + 3] };
    *(s16x4*)(out + (size_t)(c0 + oc) * R + r0 + orr) = v;
  }
}

// ---------------------------------------------------------------------------
// 128x128-tile GEMM, BK=64, 4 waves, single-buffered 32 KB LDS, plain
// 2-barrier loop (32 MFMA between barriers). Both-sides LDS XOR-swizzle ->
// bank-conflict free (round-10 verified). XCD-chunked block swizzle.
// MODE 0: fused q/k row-norm + mean partials, scatter bf16 -> [B,h,N,d].
// MODE 1: f32 + bias -> out.
// ---------------------------------------------------------------------------
template<int MODE>
__global__ __launch_bounds__(256) void gemm128(
    const short* __restrict__ A, const short* __restrict__ BT,
    int N, int K, int nxblk,
    short* __restrict__ qkv_out, float* __restrict__ proj_out,
    const float* __restrict__ bias, float* __restrict__ partials)
{
  __shared__ short As[128 * 64];   // 16 KB, swizzled k within each row
  __shared__ short Bs[128 * 64];   // 16 KB
  __shared__ float sred[4];

  const int tid  = threadIdx.x;
  const int lane = tid & 63;
  const int wid  = tid >> 6;
  const int wr   = wid >> 1, wc = wid & 1;

  const int nwg = (int)gridDim.x;
  const int cpx = nwg >> 3;
  const int swz = (blockIdx.x & 7) * cpx + (blockIdx.x >> 3);
  const int bx  = swz % nxblk, by = swz / nxblk;
  const int rowBase = by << 7;
  const int colBase = bx << 7;

  const int fr = lane & 15;
  const int fq = lane >> 4;        // 0..3

  const int srow8 = tid >> 3;                         // 0..31
  const int koff  = ((tid & 7) ^ (srow8 & 7)) << 3;   // pre-swizzled source k
  const short* ApS = A  + (size_t)(rowBase + srow8) * K + koff;
  const short* BpS = BT + (size_t)(colBase + srow8) * K + koff;
  short* dA = As + tid * 8;        // linear dest: byte off = 16*tid (+i*4KB)
  short* dB = Bs + tid * 8;

  int aoff[4], boff[4];
#pragma unroll
  for (int mf = 0; mf < 4; ++mf) {
    int r = wr * 64 + mf * 16 + fr;
    aoff[mf] = r * 64 + (((r >> 2) & 1) << 5) + ((fq ^ (r & 3)) << 3);
  }
#pragma unroll
  for (int nf = 0; nf < 4; ++nf) {
    int r = wc * 64 + nf * 16 + fr;
    boff[nf] = r * 64 + (((r >> 2) & 1) << 5) + ((fq ^ (r & 3)) << 3);
  }

  f32x4 acc[4][4];
#pragma unroll
  for (int i = 0; i < 4; ++i)
#pragma unroll
    for (int j = 0; j < 4; ++j) acc[i][j] = f32x4{0.f, 0.f, 0.f, 0.f};

  for (int k0 = 0; k0 < K; k0 += 64) {
    __syncthreads();
#pragma unroll
    for (int i = 0; i < 4; ++i) {
      gload16(ApS + (size_t)(i * 32) * K + k0, dA + i * 2048);
      gload16(BpS + (size_t)(i * 32) * K + k0, dB + i * 2048);
    }
    __syncthreads();

#pragma unroll
    for (int ks = 0; ks < 2; ++ks) {
      const int kx = ks << 5;
      bf16x8 a[4], b[4];
#pragma unroll
      for (int mf = 0; mf < 4; ++mf)
        a[mf] = *(const bf16x8*)(As + (aoff[mf] ^ kx));
#pragma unroll
      for (int nf = 0; nf < 4; ++nf)
        b[nf] = *(const bf16x8*)(Bs + (boff[nf] ^ kx));
#pragma unroll
      for (int mf = 0; mf < 4; ++mf)
#pragma unroll
        for (int nf = 0; nf < 4; ++nf)
          acc[mf][nf] = __builtin_amdgcn_mfma_f32_16x16x32_bf16(a[mf], b[nf], acc[mf][nf], 0, 0, 0);
    }
  }

  // ---- epilogue: D frag layout col = lane&15, row = fq*4 + e ----
  if (MODE == 0) {
    const int b    = rowBase >> 10;
    const int n0   = (rowBase & 1023) + wr * 64 + (fq << 2);
    const int part = colBase / 768;                   // block-uniform
    const int hd   = ((colBase - part * 768) >> 6) + wc;
    float psum = 0.f;

    if (part < 2) {
      float ss[4][4];
#pragma unroll
      for (int i = 0; i < 4; ++i)
#pragma unroll
        for (int e = 0; e < 4; ++e) {
          float s = 0.f;
#pragma unroll
          for (int j = 0; j < 4; ++j) s = fmaf(acc[i][j][e], acc[i][j][e], s);
          ss[i][e] = s;
        }
#pragma unroll
      for (int m = 1; m < 16; m <<= 1)
#pragma unroll
        for (int i = 0; i < 4; ++i)
#pragma unroll
          for (int e = 0; e < 4; ++e) ss[i][e] += __shfl_xor(ss[i][e], m);
#pragma unroll
      for (int i = 0; i < 4; ++i)
#pragma unroll
        for (int e = 0; e < 4; ++e) ss[i][e] = rsqrtf(ss[i][e]);
#pragma unroll
      for (int i = 0; i < 4; ++i)
#pragma unroll
        for (int j = 0; j < 4; ++j)
#pragma unroll
          for (int e = 0; e < 4; ++e) {
            acc[i][j][e] *= ss[i][e];
            psum += acc[i][j][e];
          }
    }

    const size_t hbase = (size_t)part * QKV_E + ((size_t)(b * 12 + hd) << 16);
#pragma unroll
    for (int j = 0; j < 4; ++j) {
      const int dd = j * 16 + fr;
#pragma unroll
      for (int i = 0; i < 4; ++i)
#pragma unroll
        for (int e = 0; e < 4; ++e)
          qkv_out[hbase + ((size_t)(n0 + i * 16 + e) << 6) + dd] = f2b(acc[i][j][e]);
    }

    if (part < 2) {          // block-uniform branch: barrier is safe
#pragma unroll
      for (int m = 1; m < 64; m <<= 1) psum += __shfl_xor(psum, m);
      if (lane == 0) sred[wid] = psum;
      __syncthreads();
      if (tid == 0)
        partials[part * PARTN + by * 12 + (bx - part * 6)] =
            sred[0] + sred[1] + sred[2] + sred[3];
    }
  } else {
    const int gr0 = rowBase + wr * 64 + (fq << 2);
#pragma unroll
    for (int j = 0; j < 4; ++j) {
      int gc = colBase + wc * 64 + j * 16 + fr;
      float bj = bias[gc];
#pragma unroll
      for (int i = 0; i < 4; ++i)
#pragma unroll
        for (int e = 0; e < 4; ++e)
          proj_out[(size_t)(gr0 + i * 16 + e) * N + gc] = acc[i][j][e] + bj;
    }
  }
}

__global__ __launch_bounds__(256) void mean_reduce_kernel(
    const float* __restrict__ partials, float* __restrict__ means)
{
  float sq = 0.f, sk = 0.f;
  for (int i = threadIdx.x; i < PARTN; i += 256) {
    sq += partials[i]; sk += partials[PARTN + i];
  }
#pragma unroll
  for (int o = 32; o; o >>= 1) { sq += __shfl_xor(sq, o); sk += __shfl_xor(sk, o); }
  __shared__ float s[8];
  int wid = threadIdx.x >> 6, lane = threadIdx.x & 63;
  if (lane == 0) { s[wid] = sq; s[4 + wid] = sk; }
  __syncthreads();
  if (threadIdx.x == 0) {
    means[0] = (s[0] + s[1] + s[2] + s[3]) / 12582912.f;
    means[1] = (s[4] + s[5] + s[6] + s[7]) / 12582912.f;
  }
}

// ---------------------------------------------------------------------------
// attn partials via MFMA (round-12 verified: 80us scalar -> MFMA)
// ---------------------------------------------------------------------------
__global__ __launch_bounds__(256) void attn_part_kernel(
    const short* __restrict__ k, const short* __restrict__ v,
    const float* __restrict__ means, float* __restrict__ part)
{
  __shared__ short kt[64][136];
  __shared__ short vt[64][136];
  const int tid = threadIdx.x, lane = tid & 63, w = tid >> 6;
  const int bh = blockIdx.x >> 2;
  const int c  = blockIdx.x & 3;
  const float mk = means[1];
  const short* kb = k + ((size_t)bh << 16);
  const short* vb = v + ((size_t)bh << 16);

  const int nl = tid & 31;         // token-within-32
  const int dg = tid >> 5;         // d-group 0..7
  const int fr = lane & 15, fq = lane >> 4;

  f32x4 acc[4];
#pragma unroll
  for (int e = 0; e < 4; ++e) acc[e] = f32x4{0.f, 0.f, 0.f, 0.f};

  for (int s = 0; s < 2; ++s) {
    __syncthreads();               // prior compute done before overwrite
#pragma unroll
    for (int p = 0; p < 4; ++p) {
      int r = p * 32 + nl;         // 0..127 local token
      int n = (c << 8) + (s << 7) + r;
      bf16x8 kv8 = *(const bf16x8*)(kb + (n << 6) + dg * 8);
      bf16x8 vv8 = *(const bf16x8*)(vb + (n << 6) + dg * 8);
#pragma unroll
      for (int j = 0; j < 8; ++j) {
        kt[dg * 8 + j][r] = (b2f(kv8[j]) > mk) ? (short)0x3F80 : (short)0;
        vt[dg * 8 + j][r] = vv8[j];
      }
    }
    __syncthreads();
#pragma unroll
    for (int ks = 0; ks < 4; ++ks) {
      const int nloc = ks * 32 + fq * 8;
      bf16x8 af = *(const bf16x8*)(&kt[w * 16 + fr][nloc]);
#pragma unroll
      for (int nf = 0; nf < 4; ++nf) {
        bf16x8 bfr = *(const bf16x8*)(&vt[nf * 16 + fr][nloc]);
        acc[nf] = __builtin_amdgcn_mfma_f32_16x16x32_bf16(af, bfr, acc[nf], 0, 0, 0);
      }
    }
  }
  float* pp = part + ((size_t)blockIdx.x << 12);
#pragma unroll
  for (int nf = 0; nf < 4; ++nf)
#pragma unroll
    for (int ee = 0; ee < 4; ++ee)
      pp[(w * 16 + fq * 4 + ee) * 64 + nf * 16 + fr] = acc[nf][ee];
}

// separate reduce -> attn f32 [192][64 d][64 e]
__global__ __launch_bounds__(256) void attn_reduce_kernel(
    const float* __restrict__ part, float* __restrict__ attn)
{
  int idx = blockIdx.x * 256 + threadIdx.x;   // over 192*4096
  int bh  = idx >> 12;
  int off = idx & 4095;
  float s = 0.f;
#pragma unroll
  for (int c = 0; c < ACH; ++c)
    s += part[(((size_t)bh * ACH + c) << 12) + off];
  attn[idx] = s;
}

// ---------------------------------------------------------------------------
// out rows via MFMA: P = qbits[128x64] @ attn[64x64] per (bh, 128-row chunk).
// Kills the col[64] register hoist that the allocator kept spilling
// (r10/r13/r14: VGPR=48, 100-176us — LDS 17KB let it target 8 waves/SIMD ->
// 64-VGPR budget). A-operand built directly from q>mean (bf16 1/0, exact);
// B from attn staged bf16 in LDS. Epilogue: 16-lane shfl row-norm + conv
// (verified pattern). Strides 68 -> fq-groups on disjoint banks.
// ---------------------------------------------------------------------------
__global__ __launch_bounds__(256) void out_kernel(
    const short* __restrict__ q, const short* __restrict__ v,
    const float* __restrict__ attn, const float* __restrict__ means,
    const float* __restrict__ wd, short* __restrict__ mid)
{
  __shared__ short v_s[136 * 68];     // v rows n0-4 .. n0+131, stride 68
  __shared__ short at_s[64 * 68];     // attn bf16 [d][e], stride 68
  const int tid = threadIdx.x, lane = tid & 63, w = tid >> 6;
  const int bh = blockIdx.x >> 3;
  const int n0 = (blockIdx.x & 7) << 7;
  const int h  = bh % 12;
  const int b  = bh / 12;
  const int fr = lane & 15, fq = lane >> 4;

  const short* vb = v + ((size_t)bh << 16);
  for (int i = tid; i < 2176; i += 256) {
    int r = i >> 4, c = (i & 15) << 2;
    int nn = n0 - 4 + r;
    s16x4 val = {0, 0, 0, 0};
    if (nn >= 0 && nn < N_TOK) val = *(const s16x4*)(vb + (nn << 6) + c);
    *(s16x4*)(v_s + r * 68 + c) = val;
  }
  const float* ab = attn + ((size_t)bh << 12);
  for (int i = tid; i < 4096; i += 256)
    at_s[(i >> 6) * 68 + (i & 63)] = f2b(ab[i]);

  const float mq = means[0];
  float wc9[9];
#pragma unroll
  for (int j = 0; j < 9; ++j) wc9[j] = wd[h * 9 + j];
  __syncthreads();

  const short* qb = q + ((size_t)bh << 16);
  f32x4 acc[2][4];
#pragma unroll
  for (int mf = 0; mf < 2; ++mf)
#pragma unroll
    for (int nf = 0; nf < 4; ++nf) acc[mf][nf] = f32x4{0.f, 0.f, 0.f, 0.f};

#pragma unroll
  for (int ks = 0; ks < 2; ++ks) {
    bf16x8 bfr[4];
#pragma unroll
    for (int nf = 0; nf < 4; ++nf) {
      bf16x8 t;
#pragma unroll
      for (int j = 0; j < 8; ++j)
        t[j] = at_s[(ks * 32 + fq * 8 + j) * 68 + nf * 16 + fr];
      bfr[nf] = t;
    }
#pragma unroll
    for (int mf = 0; mf < 2; ++mf) {
      int n = n0 + w * 32 + mf * 16 + fr;
      bf16x8 qv8 = *(const bf16x8*)(qb + ((size_t)n << 6) + ks * 32 + fq * 8);
      bf16x8 af;
#pragma unroll
      for (int j = 0; j < 8; ++j)
        af[j] = ((b2f(qv8[j]) - mq) > 0.f) ? (short)0x3F80 : (short)0;
#pragma unroll
      for (int nf = 0; nf < 4; ++nf)
        acc[mf][nf] = __builtin_amdgcn_mfma_f32_16x16x32_bf16(af, bfr[nf], acc[mf][nf], 0, 0, 0);
    }
  }

  // epilogue: lane holds e = nf*16+fr for rows w*32 + mf*16 + fq*4 + ee
  const float inv_pi = 0.3183098861837907f;
#pragma unroll
  for (int mf = 0; mf < 2; ++mf)
#pragma unroll
    for (int ee = 0; ee < 4; ++ee) {
      const int lrow = w * 32 + mf * 16 + fq * 4 + ee;   // 0..127
      float o[4];
      float ss = 0.f;
#pragma unroll
      for (int nf = 0; nf < 4; ++nf) {
        float vv = b2f(v_s[(lrow + 4) * 68 + nf * 16 + fr]);
        o[nf] = 0.5f * vv + acc[mf][nf][ee] * inv_pi;
        ss = fmaf(o[nf], o[nf], ss);
      }
#pragma unroll
      for (int m = 1; m < 16; m <<= 1) ss += __shfl_xor(ss, m);
      const float rn = rsqrtf(ss);
      const size_t obase = (size_t)((b << 10) | (n0 + lrow)) * 768 + (h << 6) + fr;
#pragma unroll
      for (int nf = 0; nf < 4; ++nf) {
        float oo = o[nf] * rn;
#pragma unroll
        for (int j = 0; j < 9; ++j)
          oo = fmaf(wc9[j], b2f(v_s[(lrow + j) * 68 + nf * 16 + fr]), oo);
        mid[obase + nf * 16] = f2b(oo);
      }
    }
}

extern "C" void kernel_launch(void* const* d_in, const int* in_sizes, int n_in,
                              void* d_out, int out_size, void* d_ws, size_t ws_size,
                              hipStream_t stream) {
  (void)in_sizes; (void)n_in; (void)out_size; (void)ws_size;
  const float* x       = (const float*)d_in[0];
  const float* w_qkv   = (const float*)d_in[3];
  const float* w_dconv = (const float*)d_in[4];
  const float* w_proj  = (const float*)d_in[5];
  const float* b_proj  = (const float*)d_in[6];

  // ---- workspace layout (phase-safe aliasing), ~130.5 MB ----
  char* ws = (char*)d_ws;
  short* qbuf = (short*)ws;                         // 3*QKV_E shorts
  short* kbuf = qbuf + QKV_E;
  short* vbuf = kbuf + QKV_E;
  char*  r2   = ws + (size_t)3 * QKV_E * 2;         // 3.54 MB region:
  short* wqkvT    = (short*)r2;                     //   phases 0-1 (3.54 MB)
  float* attn     = (float*)r2;                     //   phases 4-5 (3.15 MB)
  short* mid  = (short*)(r2 + 3538944);             // 25.2 MB, phases 5-6
  float* partials = (float*)mid;                    //   phases 1-2 (12 KB) —
                                                    //   mid unwritten till ph5
  char*  r4   = (char*)mid + (size_t)16384 * 768 * 2;
  short* xb        = (short*)r4;                    // 25.2 MB, phases 0-1
  float* attn_part = (float*)r4;                    //   reused ph 3-4 (12.6 MB)
  short* wprojT = (short*)(r4 + (size_t)QKV_E * 2); // 1.18 MB, phases 0,6
  float* means  = (float*)((char*)wprojT + (size_t)768 * 768 * 2);

  // 0) convert x -> bf16; transpose+convert both weights (one dispatch)
  cvt_bf16_kernel<<<QKV_E / 8 / 256, 256, 0, stream>>>(x, xb, QKV_E / 8);
  dim3 gt(48, 12);
  transpose_cvt2_kernel<<<gt, 256, 0, stream>>>(w_qkv, wqkvT, w_proj, wprojT);

  // 1) QKV GEMM (+fused q/k row-norm + mean partials) -> q,k,v [B,h,N,d]
  gemm128<0><<<(2304 / 128) * (16384 / 128), 256, 0, stream>>>(
      xb, wqkvT, 2304, 768, 18, qbuf, nullptr, nullptr, partials);

  // 2) global means of normalized q,k
  mean_reduce_kernel<<<1, 256, 0, stream>>>(partials, means);

  // 3) attn partials = binarized(k)^T v via MFMA
  attn_part_kernel<<<B_ * HEADS_ * ACH, 256, 0, stream>>>(kbuf, vbuf, means, attn_part);

  // 4) reduce partials -> attn [192][64][64]
  attn_reduce_kernel<<<B_ * HEADS_ * 4096 / 256, 256, 0, stream>>>(attn_part, attn);

  // 5) out rows (MFMA qbits @ attn) -> mid bf16 [B,N,768]
  out_kernel<<<ROWS_ / 128, 256, 0, stream>>>(qbuf, vbuf, attn, means, w_dconv, mid);

  // 6) projection: mid @ wprojT^T + b_proj -> d_out f32
  gemm128<1><<<(768 / 128) * (16384 / 128), 256, 0, stream>>>(
      mid, wprojT, 768, 768, 6, nullptr, (float*)d_out, b_proj, nullptr);
}